// Round 9
// baseline (495.063 us; speedup 1.0000x reference)
//
#include <hip/hip_runtime.h>

// RGCN 2-layer, basis decomposition, mean aggregation - MFMA + compact CSR.
// N=50000, E=1.6M, R=8, feat 128->128->64.
//
// Round-9: replace padded ELL (25.6MB, 100MB write-amplified) with compact
// 4-aligned CSR (<=5.6MB): hist (fire-forget atomics) -> wave-aggregated bump
// offsets -> fill (dependent atomic, L2-sized scatter). Layer kernels keep the
// round-8 full-residency structure (17.4KB LDS, 8 blk/CU), read packed{off,cnt}
// + csr, and use nontemporal epilogue stores to protect the gather cache.

#define N_NODES 50000
#define N_EDGES 1600000
#define N_REL   8
#define CAP     32
#define NSEG    (N_REL * N_NODES)

typedef __attribute__((ext_vector_type(8))) short short8;
typedef __attribute__((ext_vector_type(4))) float f32x4;

__device__ __forceinline__ ushort f2bf(float x) {
    unsigned u = __builtin_bit_cast(unsigned, x);
    u += 0x7FFFu + ((u >> 16) & 1u);   // RNE
    return (ushort)(u >> 16);
}
__device__ __forceinline__ float u2f(unsigned u) {
    return __builtin_bit_cast(float, u);
}

__global__ void zero_i32_kernel(int* __restrict__ p, int n) {
    int i = blockIdx.x * 256 + threadIdx.x;
    if (i < n) p[i] = 0;
}

// x (N,128) f32 -> xbf ((N+1),128) bf16, row N zeroed (gather sentinel).
__global__ void to_bf16_kernel(const float* __restrict__ in,
                               ushort* __restrict__ out) {
    int i = blockIdx.x * 256 + threadIdx.x;
    int total = (N_NODES + 1) * 16;
    if (i >= total) return;
    int base = i * 8;
    short8 v;
    if (base < N_NODES * 128) {
        f32x4 a = *(const f32x4*)(in + base);
        f32x4 b = *(const f32x4*)(in + base + 4);
        v = (short8){(short)f2bf(a.x), (short)f2bf(a.y), (short)f2bf(a.z),
                     (short)f2bf(a.w), (short)f2bf(b.x), (short)f2bf(b.y),
                     (short)f2bf(b.z), (short)f2bf(b.w)};
    } else {
        v = (short8){0, 0, 0, 0, 0, 0, 0, 0};
    }
    *(short8*)(out + base) = v;
}

// Wt[(r*outc + n)*128 + k] = bf16( sum_b comp[r,b]*basis[b,k,n] ), r==8 -> root
__global__ void compose_wt_kernel(const float* __restrict__ basis,
                                  const float* __restrict__ comp,
                                  const float* __restrict__ root,
                                  ushort* __restrict__ Wt,
                                  int outc, int total) {
    int i = blockIdx.x * 256 + threadIdx.x;
    if (i >= total) return;
    int per_r = outc << 7;
    int r = i / per_r;
    int rem = i - r * per_r;
    int n = rem >> 7;
    int k = rem & 127;
    float s;
    if (r == N_REL) {
        s = root[k * outc + n];
    } else {
        s = 0.f;
#pragma unroll
        for (int b = 0; b < 4; ++b)
            s += comp[r * 4 + b] * basis[(b * 128 + k) * outc + n];
    }
    Wt[i] = f2bf(s);
}

// Pass 1: per-seg degree histogram (atomic result unused -> fire-and-forget).
__global__ void hist_kernel(const int* __restrict__ A,
                            const int* __restrict__ et,
                            int* __restrict__ cnt) {
    int e = blockIdx.x * 256 + threadIdx.x;
    if (e >= N_EDGES) return;
    int d = __builtin_nontemporal_load(A + N_EDGES + e);
    int t = __builtin_nontemporal_load(et + e);
    atomicAdd(&cnt[t * N_NODES + d], 1);
}

// Pass 2: bump-allocate 4-aligned CSR chunks; one global atomic per wave.
// packed[seg] = {off (u16 units, %4==0), cnt}.
__global__ void off_kernel(const int* __restrict__ cnt,
                           int2* __restrict__ packed,
                           int* __restrict__ gcur) {
    int s = blockIdx.x * 256 + threadIdx.x;
    int lane = threadIdx.x & 63;
    int c = (s < NSEG) ? cnt[s] : 0;
    int need = (c + 3) & ~3;
    int pre = need;
#pragma unroll
    for (int o = 1; o < 64; o <<= 1) {
        int v = __shfl_up(pre, o, 64);
        if (lane >= o) pre += v;
    }
    int total = __shfl(pre, 63, 64);
    int base = 0;
    if (lane == 63) base = atomicAdd(gcur, total);
    base = __shfl(base, 63, 64);
    if (s < NSEG) packed[s] = make_int2(base + pre - need, c);
}

// Pass 3: scatter srcs into the compact CSR (footprint ~5.6MB, L2-sized).
__global__ void fill_kernel(const int* __restrict__ A,
                            const int* __restrict__ et,
                            const int2* __restrict__ packed,
                            int* __restrict__ wcnt,
                            ushort* __restrict__ csr) {
    int e = blockIdx.x * 256 + threadIdx.x;
    if (e >= N_EDGES) return;
    int sv = __builtin_nontemporal_load(A + e);
    int d  = __builtin_nontemporal_load(A + N_EDGES + e);
    int t  = __builtin_nontemporal_load(et + e);
    int seg = t * N_NODES + d;
    int slot = atomicAdd(&wcnt[seg], 1);
    int off = packed[seg].x;
    csr[(size_t)off + slot] = (ushort)sv;   // alloc = (cnt+3)&~3 >= slot+1
}

template <int OUTC, bool RELU, bool BF16OUT>
__global__ __launch_bounds__(256, 8)
void rgcn_layer_mfma(const ushort* __restrict__ xbf,   // (N+1,128) bf16
                     const int2* __restrict__ packed,  // (R*N,) {off,cnt}
                     const ushort* __restrict__ csr,   // compact u16 srcs
                     const ushort* __restrict__ Wt,    // (R+1,OUTC,128) bf16
                     const float* __restrict__ bias,   // (OUTC,)
                     void* __restrict__ outp) {        // (N,OUTC)
    constexpr int LDK = 136;        // padded k-stride (272 B rows)
    constexpr int TN  = 32;
    constexpr int NCH = OUTC / 32;  // 32-row W chunks (4 / 2) = acc tiles/wave

    __shared__ ushort meanT[TN * LDK];   // 8.7 KB
    __shared__ ushort Wl[32 * LDK];      // 8.7 KB -> total 17.4 KB, 8 blk/CU

    const int tid   = threadIdx.x;
    const int lane  = tid & 63;
    const int wave  = tid >> 6;
    const int nbase = blockIdx.x * TN;

    // gather mapping: 16 lanes per node, lane j owns features [8j,8j+8)
    const int g  = tid >> 4;
    const int j  = tid & 15;
    const int j8 = j * 8;
    const int gb = lane & 48;

    // MFMA mapping
    const int rt = wave & 1;          // 16-node row tile
    const int ch = wave >> 1;         // 16-col half within a 32-col W chunk
    const int lr = lane & 15;
    const int kc = (lane >> 4) * 8;

    f32x4 acc[NCH];
#pragma unroll
    for (int t = 0; t < NCH; ++t) acc[t] = (f32x4){0.f, 0.f, 0.f, 0.f};

    for (int r = 0; r <= N_REL; ++r) {
        // ---- gather-mean 32 nodes into meanT (two passes, 4-deep) ----
#pragma unroll
        for (int p = 0; p < 2; ++p) {
            int a  = p * 16 + g;
            int gn = nbase + a;
            short8 sv = (short8){0, 0, 0, 0, 0, 0, 0, 0};
            if (gn < N_NODES) {
                if (r == N_REL) {
                    sv = *(const short8*)(xbf + (size_t)gn * 128 + j8);
                } else {
                    int seg = r * N_NODES + gn;
                    int2 oc = packed[seg];
                    int c   = oc.y;
                    int cc  = c < CAP ? c : CAP;
                    // lane j holds slots {2j, 2j+1}; off%4==0 -> dword aligned
                    uint pre = *(const uint*)(csr + (size_t)oc.x + 2 * j);
                    f32x4 s0 = (f32x4){0.f, 0.f, 0.f, 0.f};
                    f32x4 s1 = (f32x4){0.f, 0.f, 0.f, 0.f};
                    int ccr = (cc + 3) & ~3;
                    for (int e = 0; e < ccr; e += 4) {
                        uint ua = __shfl(pre, gb + (e >> 1), 64);
                        uint ub = __shfl(pre, gb + (e >> 1) + 1, 64);
                        int i0 = (e + 0 < cc) ? (int)(ua & 0xFFFFu) : N_NODES;
                        int i1 = (e + 1 < cc) ? (int)(ua >> 16)     : N_NODES;
                        int i2 = (e + 2 < cc) ? (int)(ub & 0xFFFFu) : N_NODES;
                        int i3 = (e + 3 < cc) ? (int)(ub >> 16)     : N_NODES;
                        short8 v0 = *(const short8*)(xbf + (size_t)i0 * 128 + j8);
                        short8 v1 = *(const short8*)(xbf + (size_t)i1 * 128 + j8);
                        short8 v2 = *(const short8*)(xbf + (size_t)i2 * 128 + j8);
                        short8 v3 = *(const short8*)(xbf + (size_t)i3 * 128 + j8);
#pragma unroll
                        for (int u = 0; u < 4; ++u) {
                            short8 v = (u == 0) ? v0 : (u == 1) ? v1
                                     : (u == 2) ? v2 : v3;
                            uint4 w = __builtin_bit_cast(uint4, v);
                            s0.x += u2f(w.x << 16);
                            s0.y += u2f(w.x & 0xFFFF0000u);
                            s0.z += u2f(w.y << 16);
                            s0.w += u2f(w.y & 0xFFFF0000u);
                            s1.x += u2f(w.z << 16);
                            s1.y += u2f(w.z & 0xFFFF0000u);
                            s1.z += u2f(w.w << 16);
                            s1.w += u2f(w.w & 0xFFFF0000u);
                        }
                    }
                    float inv = 1.f / (float)(c > 1 ? c : 1);
                    s0 *= inv;
                    s1 *= inv;
                    sv = (short8){(short)f2bf(s0.x), (short)f2bf(s0.y),
                                  (short)f2bf(s0.z), (short)f2bf(s0.w),
                                  (short)f2bf(s1.x), (short)f2bf(s1.y),
                                  (short)f2bf(s1.z), (short)f2bf(s1.w)};
                }
            }
            *(short8*)&meanT[a * LDK + j8] = sv;
        }
        __syncthreads();   // meanT ready; prev r's MFMA done -> Wl writable

        // A-fragments for this r
        short8 af[4];
        const int m = rt * 16 + lr;
#pragma unroll
        for (int ks = 0; ks < 4; ++ks)
            af[ks] = *(const short8*)&meanT[m * LDK + ks * 32 + kc];

        // ---- per 32-row W chunk: stage -> sync -> MFMA (-> sync) ----
#pragma unroll
        for (int c = 0; c < NCH; ++c) {
            {   // stage 32 rows of W_r^T (coalesced float4, 2 per thread)
                const float4* src =
                    (const float4*)(Wt + ((size_t)r * OUTC + c * 32) * 128);
#pragma unroll
                for (int q = 0; q < 2; ++q) {
                    int idx = tid + q * 256;
                    int n   = idx >> 4;
                    int k8  = idx & 15;
                    *(float4*)&Wl[n * LDK + k8 * 8] = src[idx];
                }
            }
            __syncthreads();          // Wl ready
            const int n = ch * 16 + lr;     // row within chunk
            f32x4 a = acc[c];
#pragma unroll
            for (int ks = 0; ks < 4; ++ks) {
                short8 bf = *(const short8*)&Wl[n * LDK + ks * 32 + kc];
                a = __builtin_amdgcn_mfma_f32_16x16x32_bf16(af[ks], bf, a,
                                                            0, 0, 0);
            }
            acc[c] = a;
            if (c + 1 < NCH) __syncthreads();  // MFMA done reading Wl
        }
    }

    // ---- epilogue: bias (+relu), nontemporal stores (protect gather cache) ----
    const int rq = (lane >> 4) * 4;
#pragma unroll
    for (int t = 0; t < NCH; ++t) {
        int col  = t * 32 + ch * 16 + lr;
        float bv = bias[col];
#pragma unroll
        for (int q = 0; q < 4; ++q) {
            int node = nbase + rt * 16 + rq + q;
            if (node < N_NODES) {
                float v = acc[t][q] + bv;
                if (RELU) v = fmaxf(v, 0.f);
                if (BF16OUT)
                    __builtin_nontemporal_store(
                        f2bf(v), (ushort*)outp + (size_t)node * OUTC + col);
                else
                    __builtin_nontemporal_store(
                        v, (float*)outp + (size_t)node * OUTC + col);
            }
        }
    }
}

extern "C" void kernel_launch(void* const* d_in, const int* in_sizes, int n_in,
                              void* d_out, int out_size, void* d_ws, size_t ws_size,
                              hipStream_t stream) {
    const float* x        = (const float*)d_in[0];
    const int*   A        = (const int*)d_in[1];
    const int*   etype    = (const int*)d_in[2];
    const float* w1_basis = (const float*)d_in[3];
    const float* w1_comp  = (const float*)d_in[4];
    const float* w1_root  = (const float*)d_in[5];
    const float* w1_bias  = (const float*)d_in[6];
    const float* w2_basis = (const float*)d_in[7];
    const float* w2_comp  = (const float*)d_in[8];
    const float* w2_root  = (const float*)d_in[9];
    const float* w2_bias  = (const float*)d_in[10];
    float* out = (float*)d_out;

    char* ws = (char*)d_ws;
    ushort* Wt1  = (ushort*)(ws);                   // 294,912 B
    ushort* Wt2  = (ushort*)(ws + (512 << 10));     // 147,456 B
    int*    cnt  = (int*)(ws + (1 << 20));          // NSEG ints
    int*    wcnt = cnt + NSEG;                      // NSEG ints
    int*    gcur = wcnt + NSEG;                     // 1 int  (zeroed together)
    ushort* x_bf = (ushort*)(ws + (5ull << 20));    // 12.8 MB ((N+1)*128)
    ushort* h_bf = (ushort*)(ws + (18ull << 20));   // 12.8 MB
    int2*   packed = (int2*)(ws + (31ull << 20));   // 3.2 MB
    ushort* csr  = (ushort*)(ws + (35ull << 20));   // <=5.6 MB + slack

    zero_i32_kernel<<<(2 * NSEG + 1 + 255) / 256, 256, 0, stream>>>(
        cnt, 2 * NSEG + 1);
    to_bf16_kernel<<<((N_NODES + 1) * 16 + 255) / 256, 256, 0, stream>>>(x, x_bf);
    zero_i32_kernel<<<1, 64, 0, stream>>>((int*)(h_bf + (size_t)N_NODES * 128), 64);
    compose_wt_kernel<<<(9 * 128 * 128 + 255) / 256, 256, 0, stream>>>(
        w1_basis, w1_comp, w1_root, Wt1, 128, 9 * 128 * 128);
    compose_wt_kernel<<<(9 * 64 * 128 + 255) / 256, 256, 0, stream>>>(
        w2_basis, w2_comp, w2_root, Wt2, 64, 9 * 64 * 128);

    hist_kernel<<<(N_EDGES + 255) / 256, 256, 0, stream>>>(A, etype, cnt);
    off_kernel<<<(NSEG + 255) / 256, 256, 0, stream>>>(cnt, packed, gcur);
    fill_kernel<<<(N_EDGES + 255) / 256, 256, 0, stream>>>(
        A, etype, packed, wcnt, csr);

    int grid = (N_NODES + 31) / 32;  // 1563
    rgcn_layer_mfma<128, true, true><<<grid, 256, 0, stream>>>(
        x_bf, packed, csr, Wt1, w1_bias, h_bf);
    rgcn_layer_mfma<64, false, false><<<grid, 256, 0, stream>>>(
        h_bf, packed, csr, Wt2, w2_bias, out);
}

// Round 10
// 369.895 us; speedup vs baseline: 1.3384x; 1.3384x over previous
//
#include <hip/hip_runtime.h>

// RGCN 2-layer, basis decomposition, mean aggregation - MFMA, single-atomic-pass.
// N=50000, E=1.6M, R=8, feat 128->128->64.
//
// Round-10: r9's layer kernels (17.4KB LDS full-residency, nt epilogue stores)
// + r8's single fused build (one atomicAdd per edge gives hist AND slot; u16
// ELL CAP=32 = one 64B line per segment). The 3-pass CSR build cost ~2 atomic
// passes (~110us each, memory-side atomics are the floor); this has exactly 1.

#define N_NODES 50000
#define N_EDGES 1600000
#define N_REL   8
#define CAP     32
#define NSEG    (N_REL * N_NODES)

typedef __attribute__((ext_vector_type(8))) short short8;
typedef __attribute__((ext_vector_type(4))) float f32x4;

__device__ __forceinline__ ushort f2bf(float x) {
    unsigned u = __builtin_bit_cast(unsigned, x);
    u += 0x7FFFu + ((u >> 16) & 1u);   // RNE
    return (ushort)(u >> 16);
}
__device__ __forceinline__ float u2f(unsigned u) {
    return __builtin_bit_cast(float, u);
}

__global__ void zero_i32_kernel(int* __restrict__ p, int n) {
    int i = blockIdx.x * 256 + threadIdx.x;
    if (i < n) p[i] = 0;
}

// x (N,128) f32 -> xbf ((N+1),128) bf16, row N zeroed (gather sentinel).
__global__ void to_bf16_kernel(const float* __restrict__ in,
                               ushort* __restrict__ out) {
    int i = blockIdx.x * 256 + threadIdx.x;
    int total = (N_NODES + 1) * 16;
    if (i >= total) return;
    int base = i * 8;
    short8 v;
    if (base < N_NODES * 128) {
        f32x4 a = *(const f32x4*)(in + base);
        f32x4 b = *(const f32x4*)(in + base + 4);
        v = (short8){(short)f2bf(a.x), (short)f2bf(a.y), (short)f2bf(a.z),
                     (short)f2bf(a.w), (short)f2bf(b.x), (short)f2bf(b.y),
                     (short)f2bf(b.z), (short)f2bf(b.w)};
    } else {
        v = (short8){0, 0, 0, 0, 0, 0, 0, 0};
    }
    *(short8*)(out + base) = v;
}

// Wt[(r*outc + n)*128 + k] = bf16( sum_b comp[r,b]*basis[b,k,n] ), r==8 -> root
__global__ void compose_wt_kernel(const float* __restrict__ basis,
                                  const float* __restrict__ comp,
                                  const float* __restrict__ root,
                                  ushort* __restrict__ Wt,
                                  int outc, int total) {
    int i = blockIdx.x * 256 + threadIdx.x;
    if (i >= total) return;
    int per_r = outc << 7;
    int r = i / per_r;
    int rem = i - r * per_r;
    int n = rem >> 7;
    int k = rem & 127;
    float s;
    if (r == N_REL) {
        s = root[k * outc + n];
    } else {
        s = 0.f;
#pragma unroll
        for (int b = 0; b < 4; ++b)
            s += comp[r * 4 + b] * basis[(b * 128 + k) * outc + n];
    }
    Wt[i] = f2bf(s);
}

// Single pass: one atomicAdd per edge yields histogram AND slot.
__global__ void build_ell_kernel(const int* __restrict__ A,
                                 const int* __restrict__ etype,
                                 int* __restrict__ cnt,
                                 ushort* __restrict__ ell) {   // (R*N, CAP) u16
    int e = blockIdx.x * 256 + threadIdx.x;
    if (e >= N_EDGES) return;
    int s = __builtin_nontemporal_load(A + e);
    int d = __builtin_nontemporal_load(A + N_EDGES + e);
    int t = __builtin_nontemporal_load(etype + e);
    int seg = t * N_NODES + d;
    int slot = atomicAdd(&cnt[seg], 1);
    if (slot < CAP) ell[(size_t)seg * CAP + slot] = (ushort)s;
}

template <int OUTC, bool RELU, bool BF16OUT>
__global__ __launch_bounds__(256, 8)
void rgcn_layer_mfma(const ushort* __restrict__ xbf,  // (N+1,128) bf16
                     const int* __restrict__ cnt,     // (R*N,)
                     const ushort* __restrict__ ell,  // (R*N,CAP) u16
                     const ushort* __restrict__ Wt,   // (R+1,OUTC,128) bf16
                     const float* __restrict__ bias,  // (OUTC,)
                     void* __restrict__ outp) {       // (N,OUTC)
    constexpr int LDK = 136;        // padded k-stride (272 B rows)
    constexpr int TN  = 32;
    constexpr int NCH = OUTC / 32;  // 32-row W chunks (4 / 2) = acc tiles/wave

    __shared__ ushort meanT[TN * LDK];   // 8.7 KB
    __shared__ ushort Wl[32 * LDK];      // 8.7 KB -> total 17.4 KB, 8 blk/CU

    const int tid   = threadIdx.x;
    const int lane  = tid & 63;
    const int wave  = tid >> 6;
    const int nbase = blockIdx.x * TN;

    // gather mapping: 16 lanes per node, lane j owns features [8j,8j+8)
    const int g  = tid >> 4;
    const int j  = tid & 15;
    const int j8 = j * 8;
    const int gb = lane & 48;

    // MFMA mapping
    const int rt = wave & 1;          // 16-node row tile
    const int ch = wave >> 1;         // 16-col half within a 32-col W chunk
    const int lr = lane & 15;
    const int kc = (lane >> 4) * 8;

    f32x4 acc[NCH];
#pragma unroll
    for (int t = 0; t < NCH; ++t) acc[t] = (f32x4){0.f, 0.f, 0.f, 0.f};

    for (int r = 0; r <= N_REL; ++r) {
        // ---- gather-mean 32 nodes into meanT (two passes, 4-deep) ----
#pragma unroll
        for (int p = 0; p < 2; ++p) {
            int a  = p * 16 + g;
            int gn = nbase + a;
            short8 sv = (short8){0, 0, 0, 0, 0, 0, 0, 0};
            if (gn < N_NODES) {
                if (r == N_REL) {
                    sv = *(const short8*)(xbf + (size_t)gn * 128 + j8);
                } else {
                    int seg = r * N_NODES + gn;
                    int c   = cnt[seg];
                    int cc  = c < CAP ? c : CAP;
                    // lane j holds slots {2j, 2j+1} of this node's 64B ELL row
                    uint pre = *(const uint*)(ell + (size_t)seg * CAP + 2 * j);
                    f32x4 s0 = (f32x4){0.f, 0.f, 0.f, 0.f};
                    f32x4 s1 = (f32x4){0.f, 0.f, 0.f, 0.f};
                    int ccr = (cc + 3) & ~3;
                    for (int e = 0; e < ccr; e += 4) {
                        uint ua = __shfl(pre, gb + (e >> 1), 64);
                        uint ub = __shfl(pre, gb + (e >> 1) + 1, 64);
                        int i0 = (e + 0 < cc) ? (int)(ua & 0xFFFFu) : N_NODES;
                        int i1 = (e + 1 < cc) ? (int)(ua >> 16)     : N_NODES;
                        int i2 = (e + 2 < cc) ? (int)(ub & 0xFFFFu) : N_NODES;
                        int i3 = (e + 3 < cc) ? (int)(ub >> 16)     : N_NODES;
                        short8 v0 = *(const short8*)(xbf + (size_t)i0 * 128 + j8);
                        short8 v1 = *(const short8*)(xbf + (size_t)i1 * 128 + j8);
                        short8 v2 = *(const short8*)(xbf + (size_t)i2 * 128 + j8);
                        short8 v3 = *(const short8*)(xbf + (size_t)i3 * 128 + j8);
#pragma unroll
                        for (int u = 0; u < 4; ++u) {
                            short8 v = (u == 0) ? v0 : (u == 1) ? v1
                                     : (u == 2) ? v2 : v3;
                            uint4 w = __builtin_bit_cast(uint4, v);
                            s0.x += u2f(w.x << 16);
                            s0.y += u2f(w.x & 0xFFFF0000u);
                            s0.z += u2f(w.y << 16);
                            s0.w += u2f(w.y & 0xFFFF0000u);
                            s1.x += u2f(w.z << 16);
                            s1.y += u2f(w.z & 0xFFFF0000u);
                            s1.z += u2f(w.w << 16);
                            s1.w += u2f(w.w & 0xFFFF0000u);
                        }
                    }
                    float inv = 1.f / (float)(c > 1 ? c : 1);
                    s0 *= inv;
                    s1 *= inv;
                    sv = (short8){(short)f2bf(s0.x), (short)f2bf(s0.y),
                                  (short)f2bf(s0.z), (short)f2bf(s0.w),
                                  (short)f2bf(s1.x), (short)f2bf(s1.y),
                                  (short)f2bf(s1.z), (short)f2bf(s1.w)};
                }
            }
            *(short8*)&meanT[a * LDK + j8] = sv;
        }
        __syncthreads();   // meanT ready; prev r's MFMA done -> Wl writable

        // A-fragments for this r
        short8 af[4];
        const int m = rt * 16 + lr;
#pragma unroll
        for (int ks = 0; ks < 4; ++ks)
            af[ks] = *(const short8*)&meanT[m * LDK + ks * 32 + kc];

        // ---- per 32-row W chunk: stage -> sync -> MFMA (-> sync) ----
#pragma unroll
        for (int c = 0; c < NCH; ++c) {
            {   // stage 32 rows of W_r^T (coalesced float4, 2 per thread)
                const float4* src =
                    (const float4*)(Wt + ((size_t)r * OUTC + c * 32) * 128);
#pragma unroll
                for (int q = 0; q < 2; ++q) {
                    int idx = tid + q * 256;
                    int n   = idx >> 4;
                    int k8  = idx & 15;
                    *(float4*)&Wl[n * LDK + k8 * 8] = src[idx];
                }
            }
            __syncthreads();          // Wl ready
            const int n = ch * 16 + lr;     // row within chunk
            f32x4 a = acc[c];
#pragma unroll
            for (int ks = 0; ks < 4; ++ks) {
                short8 bf = *(const short8*)&Wl[n * LDK + ks * 32 + kc];
                a = __builtin_amdgcn_mfma_f32_16x16x32_bf16(af[ks], bf, a,
                                                            0, 0, 0);
            }
            acc[c] = a;
            if (c + 1 < NCH) __syncthreads();  // MFMA done reading Wl
        }
    }

    // ---- epilogue: bias (+relu), nontemporal stores (protect gather cache) ----
    const int rq = (lane >> 4) * 4;
#pragma unroll
    for (int t = 0; t < NCH; ++t) {
        int col  = t * 32 + ch * 16 + lr;
        float bv = bias[col];
#pragma unroll
        for (int q = 0; q < 4; ++q) {
            int node = nbase + rt * 16 + rq + q;
            if (node < N_NODES) {
                float v = acc[t][q] + bv;
                if (RELU) v = fmaxf(v, 0.f);
                if (BF16OUT)
                    __builtin_nontemporal_store(
                        f2bf(v), (ushort*)outp + (size_t)node * OUTC + col);
                else
                    __builtin_nontemporal_store(
                        v, (float*)outp + (size_t)node * OUTC + col);
            }
        }
    }
}

extern "C" void kernel_launch(void* const* d_in, const int* in_sizes, int n_in,
                              void* d_out, int out_size, void* d_ws, size_t ws_size,
                              hipStream_t stream) {
    const float* x        = (const float*)d_in[0];
    const int*   A        = (const int*)d_in[1];
    const int*   etype    = (const int*)d_in[2];
    const float* w1_basis = (const float*)d_in[3];
    const float* w1_comp  = (const float*)d_in[4];
    const float* w1_root  = (const float*)d_in[5];
    const float* w1_bias  = (const float*)d_in[6];
    const float* w2_basis = (const float*)d_in[7];
    const float* w2_comp  = (const float*)d_in[8];
    const float* w2_root  = (const float*)d_in[9];
    const float* w2_bias  = (const float*)d_in[10];
    float* out = (float*)d_out;

    char* ws = (char*)d_ws;
    ushort* Wt1  = (ushort*)(ws);                   // 294,912 B
    ushort* Wt2  = (ushort*)(ws + (512 << 10));     // 147,456 B
    int*    cnt  = (int*)(ws + (1 << 20));          // 1.6 MB (NSEG)
    ushort* x_bf = (ushort*)(ws + (3ull << 20));    // 12.8 MB ((N+1)*128)
    ushort* h_bf = (ushort*)(ws + (16ull << 20));   // 12.8 MB
    ushort* ell  = (ushort*)(ws + (29ull << 20));   // 25.6 MB u16

    zero_i32_kernel<<<(NSEG + 255) / 256, 256, 0, stream>>>(cnt, NSEG);
    to_bf16_kernel<<<((N_NODES + 1) * 16 + 255) / 256, 256, 0, stream>>>(x, x_bf);
    zero_i32_kernel<<<1, 64, 0, stream>>>((int*)(h_bf + (size_t)N_NODES * 128), 64);
    compose_wt_kernel<<<(9 * 128 * 128 + 255) / 256, 256, 0, stream>>>(
        w1_basis, w1_comp, w1_root, Wt1, 128, 9 * 128 * 128);
    compose_wt_kernel<<<(9 * 64 * 128 + 255) / 256, 256, 0, stream>>>(
        w2_basis, w2_comp, w2_root, Wt2, 64, 9 * 64 * 128);
    build_ell_kernel<<<(N_EDGES + 255) / 256, 256, 0, stream>>>(A, etype, cnt, ell);

    int grid = (N_NODES + 31) / 32;  // 1563
    rgcn_layer_mfma<128, true, true><<<grid, 256, 0, stream>>>(
        x_bf, cnt, ell, Wt1, w1_bias, h_bf);
    rgcn_layer_mfma<64, false, false><<<grid, 256, 0, stream>>>(
        h_bf, cnt, ell, Wt2, w2_bias, out);
}

// Round 11
// 368.797 us; speedup vs baseline: 1.3424x; 1.0030x over previous
//
#include <hip/hip_runtime.h>

// RGCN 2-layer, basis decomposition, mean aggregation - MFMA, TN=64 tiles.
// N=50000, E=1.6M, R=8, feat 128->128->64.
//
// Round-11: layer kernels go TN=64 / 512 threads (8 waves): halves W-staging
// L2 traffic (450->225 MB for layer1) and per-block overheads while keeping
// ~24 waves/CU (LDS 26.1 KB, thread-capped 4 blk/CU, grid 782 fully resident).
// Build stays single-atomic-pass ELL (atomic-throughput floor ~118 us).

#define N_NODES 50000
#define N_EDGES 1600000
#define N_REL   8
#define CAP     32
#define NSEG    (N_REL * N_NODES)

typedef __attribute__((ext_vector_type(8))) short short8;
typedef __attribute__((ext_vector_type(4))) float f32x4;

__device__ __forceinline__ ushort f2bf(float x) {
    unsigned u = __builtin_bit_cast(unsigned, x);
    u += 0x7FFFu + ((u >> 16) & 1u);   // RNE
    return (ushort)(u >> 16);
}
__device__ __forceinline__ float u2f(unsigned u) {
    return __builtin_bit_cast(float, u);
}

__global__ void zero_i32_kernel(int* __restrict__ p, int n) {
    int i = blockIdx.x * 256 + threadIdx.x;
    if (i < n) p[i] = 0;
}

// x -> bf16 rows (row N zeroed) AND zero h_bf row N (gather sentinels).
__global__ void to_bf16_kernel(const float* __restrict__ in,
                               ushort* __restrict__ out,
                               ushort* __restrict__ hbf) {
    int i = blockIdx.x * 256 + threadIdx.x;
    int totx = (N_NODES + 1) * 16;
    if (i < totx) {
        int base = i * 8;
        short8 v;
        if (base < N_NODES * 128) {
            f32x4 a = *(const f32x4*)(in + base);
            f32x4 b = *(const f32x4*)(in + base + 4);
            v = (short8){(short)f2bf(a.x), (short)f2bf(a.y), (short)f2bf(a.z),
                         (short)f2bf(a.w), (short)f2bf(b.x), (short)f2bf(b.y),
                         (short)f2bf(b.z), (short)f2bf(b.w)};
        } else {
            v = (short8){0, 0, 0, 0, 0, 0, 0, 0};
        }
        *(short8*)(out + base) = v;
    } else if (i < totx + 16) {
        int idx = i - totx;
        *(short8*)(hbf + (size_t)N_NODES * 128 + idx * 8) =
            (short8){0, 0, 0, 0, 0, 0, 0, 0};
    }
}

// Both layers' W^T composed in one launch.
// Wt[(r*outc + n)*128 + k] = bf16( sum_b comp[r,b]*basis[b,k,n] ), r==8 -> root
__global__ void compose_wt_kernel(const float* __restrict__ basis1,
                                  const float* __restrict__ comp1,
                                  const float* __restrict__ root1,
                                  const float* __restrict__ basis2,
                                  const float* __restrict__ comp2,
                                  const float* __restrict__ root2,
                                  ushort* __restrict__ Wt1,
                                  ushort* __restrict__ Wt2) {
    constexpr int T1 = 9 * 128 * 128;
    constexpr int T2 = 9 * 64 * 128;
    int i = blockIdx.x * 256 + threadIdx.x;
    if (i >= T1 + T2) return;
    const float* basis;
    const float* comp;
    const float* root;
    ushort* Wt;
    int outc, ii;
    if (i < T1) {
        basis = basis1; comp = comp1; root = root1; Wt = Wt1;
        outc = 128; ii = i;
    } else {
        basis = basis2; comp = comp2; root = root2; Wt = Wt2;
        outc = 64; ii = i - T1;
    }
    int per_r = outc << 7;
    int r = ii / per_r;
    int rem = ii - r * per_r;
    int n = rem >> 7;
    int k = rem & 127;
    float s;
    if (r == N_REL) {
        s = root[k * outc + n];
    } else {
        s = 0.f;
#pragma unroll
        for (int b = 0; b < 4; ++b)
            s += comp[r * 4 + b] * basis[(b * 128 + k) * outc + n];
    }
    Wt[ii] = f2bf(s);
}

// Single pass: one atomicAdd per edge yields histogram AND slot.
__global__ void build_ell_kernel(const int* __restrict__ A,
                                 const int* __restrict__ etype,
                                 int* __restrict__ cnt,
                                 ushort* __restrict__ ell) {   // (R*N, CAP) u16
    int e = blockIdx.x * 256 + threadIdx.x;
    if (e >= N_EDGES) return;
    int s = __builtin_nontemporal_load(A + e);
    int d = __builtin_nontemporal_load(A + N_EDGES + e);
    int t = __builtin_nontemporal_load(etype + e);
    int seg = t * N_NODES + d;
    int slot = atomicAdd(&cnt[seg], 1);
    if (slot < CAP) ell[(size_t)seg * CAP + slot] = (ushort)s;
}

template <int OUTC, bool RELU, bool BF16OUT>
__global__ __launch_bounds__(512, 8)
void rgcn_layer_mfma(const ushort* __restrict__ xbf,  // (N+1,128) bf16
                     const int* __restrict__ cnt,     // (R*N,)
                     const ushort* __restrict__ ell,  // (R*N,CAP) u16
                     const ushort* __restrict__ Wt,   // (R+1,OUTC,128) bf16
                     const float* __restrict__ bias,  // (OUTC,)
                     void* __restrict__ outp) {       // (N,OUTC)
    constexpr int LDK = 136;        // padded k-stride (272 B rows)
    constexpr int TN  = 64;
    constexpr int NCH = OUTC / 32;  // 32-row W chunks (4 / 2) = acc tiles/wave

    __shared__ ushort meanT[TN * LDK];   // 17.4 KB
    __shared__ ushort Wl[32 * LDK];      // 8.7 KB -> 26.1 KB, 4 blk/CU (threads)

    const int tid   = threadIdx.x;
    const int lane  = tid & 63;
    const int wave  = tid >> 6;
    const int nbase = blockIdx.x * TN;

    // gather mapping: 16 lanes per node, lane j owns features [8j,8j+8)
    const int g  = tid >> 4;   // 0..31: node within pass
    const int j  = tid & 15;
    const int j8 = j * 8;
    const int gb = lane & 48;

    // MFMA mapping: 8 waves = 4 m-tiles x 2 col-halves
    const int rt = wave & 3;          // 16-node row tile
    const int ch = wave >> 2;         // 16-col half within a 32-col W chunk
    const int lr = lane & 15;
    const int kc = (lane >> 4) * 8;

    f32x4 acc[NCH];
#pragma unroll
    for (int t = 0; t < NCH; ++t) acc[t] = (f32x4){0.f, 0.f, 0.f, 0.f};

    for (int r = 0; r <= N_REL; ++r) {
        // ---- gather-mean 64 nodes into meanT (two passes of 32, 4-deep) ----
#pragma unroll
        for (int p = 0; p < 2; ++p) {
            int a  = p * 32 + g;
            int gn = nbase + a;
            short8 sv = (short8){0, 0, 0, 0, 0, 0, 0, 0};
            if (gn < N_NODES) {
                if (r == N_REL) {
                    sv = *(const short8*)(xbf + (size_t)gn * 128 + j8);
                } else {
                    int seg = r * N_NODES + gn;
                    int c   = cnt[seg];
                    int cc  = c < CAP ? c : CAP;
                    // lane j holds slots {2j, 2j+1} of this node's 64B ELL row
                    uint pre = *(const uint*)(ell + (size_t)seg * CAP + 2 * j);
                    f32x4 s0 = (f32x4){0.f, 0.f, 0.f, 0.f};
                    f32x4 s1 = (f32x4){0.f, 0.f, 0.f, 0.f};
                    int ccr = (cc + 3) & ~3;
                    for (int e = 0; e < ccr; e += 4) {
                        uint ua = __shfl(pre, gb + (e >> 1), 64);
                        uint ub = __shfl(pre, gb + (e >> 1) + 1, 64);
                        int i0 = (e + 0 < cc) ? (int)(ua & 0xFFFFu) : N_NODES;
                        int i1 = (e + 1 < cc) ? (int)(ua >> 16)     : N_NODES;
                        int i2 = (e + 2 < cc) ? (int)(ub & 0xFFFFu) : N_NODES;
                        int i3 = (e + 3 < cc) ? (int)(ub >> 16)     : N_NODES;
                        short8 v0 = *(const short8*)(xbf + (size_t)i0 * 128 + j8);
                        short8 v1 = *(const short8*)(xbf + (size_t)i1 * 128 + j8);
                        short8 v2 = *(const short8*)(xbf + (size_t)i2 * 128 + j8);
                        short8 v3 = *(const short8*)(xbf + (size_t)i3 * 128 + j8);
#pragma unroll
                        for (int u = 0; u < 4; ++u) {
                            short8 v = (u == 0) ? v0 : (u == 1) ? v1
                                     : (u == 2) ? v2 : v3;
                            uint4 w = __builtin_bit_cast(uint4, v);
                            s0.x += u2f(w.x << 16);
                            s0.y += u2f(w.x & 0xFFFF0000u);
                            s0.z += u2f(w.y << 16);
                            s0.w += u2f(w.y & 0xFFFF0000u);
                            s1.x += u2f(w.z << 16);
                            s1.y += u2f(w.z & 0xFFFF0000u);
                            s1.z += u2f(w.w << 16);
                            s1.w += u2f(w.w & 0xFFFF0000u);
                        }
                    }
                    float inv = 1.f / (float)(c > 1 ? c : 1);
                    s0 *= inv;
                    s1 *= inv;
                    sv = (short8){(short)f2bf(s0.x), (short)f2bf(s0.y),
                                  (short)f2bf(s0.z), (short)f2bf(s0.w),
                                  (short)f2bf(s1.x), (short)f2bf(s1.y),
                                  (short)f2bf(s1.z), (short)f2bf(s1.w)};
                }
            }
            *(short8*)&meanT[a * LDK + j8] = sv;
        }
        __syncthreads();   // meanT ready; prev r's MFMA done -> Wl writable

        // A-fragments for this r
        short8 af[4];
        const int m = rt * 16 + lr;
#pragma unroll
        for (int ks = 0; ks < 4; ++ks)
            af[ks] = *(const short8*)&meanT[m * LDK + ks * 32 + kc];

        // ---- per 32-row W chunk: stage -> sync -> MFMA (-> sync) ----
#pragma unroll
        for (int c = 0; c < NCH; ++c) {
            {   // stage 32 rows of W_r^T (512 float4s = 1 per thread)
                const float4* src =
                    (const float4*)(Wt + ((size_t)r * OUTC + c * 32) * 128);
                int n  = tid >> 4;
                int k8 = tid & 15;
                *(float4*)&Wl[n * LDK + k8 * 8] = src[tid];
            }
            __syncthreads();          // Wl ready
            const int n = ch * 16 + lr;     // row within chunk
            f32x4 a = acc[c];
#pragma unroll
            for (int ks = 0; ks < 4; ++ks) {
                short8 bf = *(const short8*)&Wl[n * LDK + ks * 32 + kc];
                a = __builtin_amdgcn_mfma_f32_16x16x32_bf16(af[ks], bf, a,
                                                            0, 0, 0);
            }
            acc[c] = a;
            if (c + 1 < NCH) __syncthreads();  // MFMA done reading Wl
        }
    }

    // ---- epilogue: bias (+relu), nontemporal stores ----
    const int rq = (lane >> 4) * 4;
#pragma unroll
    for (int t = 0; t < NCH; ++t) {
        int col  = t * 32 + ch * 16 + lr;
        float bv = bias[col];
#pragma unroll
        for (int q = 0; q < 4; ++q) {
            int node = nbase + rt * 16 + rq + q;
            if (node < N_NODES) {
                float v = acc[t][q] + bv;
                if (RELU) v = fmaxf(v, 0.f);
                if (BF16OUT)
                    __builtin_nontemporal_store(
                        f2bf(v), (ushort*)outp + (size_t)node * OUTC + col);
                else
                    __builtin_nontemporal_store(
                        v, (float*)outp + (size_t)node * OUTC + col);
            }
        }
    }
}

extern "C" void kernel_launch(void* const* d_in, const int* in_sizes, int n_in,
                              void* d_out, int out_size, void* d_ws, size_t ws_size,
                              hipStream_t stream) {
    const float* x        = (const float*)d_in[0];
    const int*   A        = (const int*)d_in[1];
    const int*   etype    = (const int*)d_in[2];
    const float* w1_basis = (const float*)d_in[3];
    const float* w1_comp  = (const float*)d_in[4];
    const float* w1_root  = (const float*)d_in[5];
    const float* w1_bias  = (const float*)d_in[6];
    const float* w2_basis = (const float*)d_in[7];
    const float* w2_comp  = (const float*)d_in[8];
    const float* w2_root  = (const float*)d_in[9];
    const float* w2_bias  = (const float*)d_in[10];
    float* out = (float*)d_out;

    char* ws = (char*)d_ws;
    ushort* Wt1  = (ushort*)(ws);                   // 294,912 B
    ushort* Wt2  = (ushort*)(ws + (512 << 10));     // 147,456 B
    int*    cnt  = (int*)(ws + (1 << 20));          // 1.6 MB (NSEG)
    ushort* x_bf = (ushort*)(ws + (3ull << 20));    // 12.8 MB ((N+1)*128)
    ushort* h_bf = (ushort*)(ws + (16ull << 20));   // 12.8 MB
    ushort* ell  = (ushort*)(ws + (29ull << 20));   // 25.6 MB u16

    zero_i32_kernel<<<(NSEG + 255) / 256, 256, 0, stream>>>(cnt, NSEG);
    to_bf16_kernel<<<((N_NODES + 1) * 16 + 16 + 255) / 256, 256, 0, stream>>>(
        x, x_bf, h_bf);
    compose_wt_kernel<<<(9 * 128 * 128 + 9 * 64 * 128 + 255) / 256, 256, 0,
                      stream>>>(w1_basis, w1_comp, w1_root,
                                w2_basis, w2_comp, w2_root, Wt1, Wt2);
    build_ell_kernel<<<(N_EDGES + 255) / 256, 256, 0, stream>>>(A, etype, cnt, ell);

    int grid = (N_NODES + 63) / 64;  // 782
    rgcn_layer_mfma<128, true, true><<<grid, 512, 0, stream>>>(
        x_bf, cnt, ell, Wt1, w1_bias, h_bf);
    rgcn_layer_mfma<64, false, false><<<grid, 512, 0, stream>>>(
        h_bf, cnt, ell, Wt2, w2_bias, out);
}

// Round 12
// 360.532 us; speedup vs baseline: 1.3731x; 1.0229x over previous
//
#include <hip/hip_runtime.h>

// RGCN 2-layer, basis decomposition, mean aggregation - MFMA, fused prep.
// N=50000, E=1.6M, R=8, feat 128->128->64.
//
// Round-12: (1) mega-kernel fuses build_ell (atomic-floor ~118us, 99% idle)
// with to_bf16 + compose as backfill blocks -> prep time + launch gaps hidden.
// (2) layer kernels (TN=32, proven 96/72us) prefetch next relation's cnt +
// ell word during the MFMA phase -> gather serial chain 3 loads -> 1.

#define N_NODES 50000
#define N_EDGES 1600000
#define N_REL   8
#define CAP     32
#define NSEG    (N_REL * N_NODES)

#define NB_BUILD 6250   // ceil(E/256)
#define NB_X     3126   // ceil((50001*16+16)/256)
#define NB_W     864    // (9*128*128 + 9*64*128)/256

typedef __attribute__((ext_vector_type(8))) short short8;
typedef __attribute__((ext_vector_type(4))) float f32x4;

__device__ __forceinline__ ushort f2bf(float x) {
    unsigned u = __builtin_bit_cast(unsigned, x);
    u += 0x7FFFu + ((u >> 16) & 1u);   // RNE
    return (ushort)(u >> 16);
}
__device__ __forceinline__ float u2f(unsigned u) {
    return __builtin_bit_cast(float, u);
}

__global__ void zero_i32_kernel(int* __restrict__ p, int n) {
    int i = blockIdx.x * 256 + threadIdx.x;
    if (i < n) p[i] = 0;
}

// One dispatch: [0,NB_BUILD) ELL build (1 edge/thread, fast-retiring blocks,
// dispatched first = critical path); then x->bf16 (+h sentinel); then both
// layers' W^T compose. Prep backfills CUs while build waits on atomics.
__global__ void mega_prep_kernel(const int* __restrict__ A,
                                 const int* __restrict__ etype,
                                 int* __restrict__ cnt,
                                 ushort* __restrict__ ell,
                                 const float* __restrict__ x,
                                 ushort* __restrict__ xbf,
                                 ushort* __restrict__ hbf,
                                 const float* __restrict__ basis1,
                                 const float* __restrict__ comp1,
                                 const float* __restrict__ root1,
                                 const float* __restrict__ basis2,
                                 const float* __restrict__ comp2,
                                 const float* __restrict__ root2,
                                 ushort* __restrict__ Wt1,
                                 ushort* __restrict__ Wt2) {
    const int bid = blockIdx.x;
    const int tid = threadIdx.x;
    if (bid < NB_BUILD) {
        // ---- build: one atomicAdd per edge gives hist AND slot ----
        int e = bid * 256 + tid;
        if (e < N_EDGES) {
            int s = __builtin_nontemporal_load(A + e);
            int d = __builtin_nontemporal_load(A + N_EDGES + e);
            int t = __builtin_nontemporal_load(etype + e);
            int seg = t * N_NODES + d;
            int slot = atomicAdd(&cnt[seg], 1);
            if (slot < CAP) ell[(size_t)seg * CAP + slot] = (ushort)s;
        }
    } else if (bid < NB_BUILD + NB_X) {
        // ---- x (N,128) f32 -> xbf ((N+1),128) bf16; zero h_bf sentinel ----
        int i = (bid - NB_BUILD) * 256 + tid;
        int totx = (N_NODES + 1) * 16;
        if (i < totx) {
            int base = i * 8;
            short8 v;
            if (base < N_NODES * 128) {
                f32x4 a = *(const f32x4*)(x + base);
                f32x4 b = *(const f32x4*)(x + base + 4);
                v = (short8){(short)f2bf(a.x), (short)f2bf(a.y), (short)f2bf(a.z),
                             (short)f2bf(a.w), (short)f2bf(b.x), (short)f2bf(b.y),
                             (short)f2bf(b.z), (short)f2bf(b.w)};
            } else {
                v = (short8){0, 0, 0, 0, 0, 0, 0, 0};
            }
            *(short8*)(xbf + base) = v;
        } else if (i < totx + 16) {
            int idx = i - totx;
            *(short8*)(hbf + (size_t)N_NODES * 128 + idx * 8) =
                (short8){0, 0, 0, 0, 0, 0, 0, 0};
        }
    } else {
        // ---- compose both W^T: Wt[(r*outc+n)*128+k], r==8 -> root ----
        constexpr int T1 = 9 * 128 * 128;
        constexpr int T2 = 9 * 64 * 128;
        int i = (bid - NB_BUILD - NB_X) * 256 + tid;
        if (i >= T1 + T2) return;
        const float* basis;
        const float* comp;
        const float* root;
        ushort* Wt;
        int outc, ii;
        if (i < T1) {
            basis = basis1; comp = comp1; root = root1; Wt = Wt1;
            outc = 128; ii = i;
        } else {
            basis = basis2; comp = comp2; root = root2; Wt = Wt2;
            outc = 64; ii = i - T1;
        }
        int per_r = outc << 7;
        int r = ii / per_r;
        int rem = ii - r * per_r;
        int n = rem >> 7;
        int k = rem & 127;
        float s;
        if (r == N_REL) {
            s = root[k * outc + n];
        } else {
            s = 0.f;
#pragma unroll
            for (int b = 0; b < 4; ++b)
                s += comp[r * 4 + b] * basis[(b * 128 + k) * outc + n];
        }
        Wt[ii] = f2bf(s);
    }
}

template <int OUTC, bool RELU, bool BF16OUT>
__global__ __launch_bounds__(256, 8)
void rgcn_layer_mfma(const ushort* __restrict__ xbf,  // (N+1,128) bf16
                     const int* __restrict__ cnt,     // (R*N,)
                     const ushort* __restrict__ ell,  // (R*N,CAP) u16
                     const ushort* __restrict__ Wt,   // (R+1,OUTC,128) bf16
                     const float* __restrict__ bias,  // (OUTC,)
                     void* __restrict__ outp) {       // (N,OUTC)
    constexpr int LDK = 136;        // padded k-stride (272 B rows)
    constexpr int TN  = 32;
    constexpr int NCH = OUTC / 32;  // 32-row W chunks (4 / 2) = acc tiles/wave

    __shared__ ushort meanT[TN * LDK];   // 8.7 KB
    __shared__ ushort Wl[32 * LDK];      // 8.7 KB -> total 17.4 KB, 8 blk/CU

    const int tid   = threadIdx.x;
    const int lane  = tid & 63;
    const int wave  = tid >> 6;
    const int nbase = blockIdx.x * TN;

    // gather mapping: 16 lanes per node, lane j owns features [8j,8j+8)
    const int g  = tid >> 4;
    const int j  = tid & 15;
    const int j8 = j * 8;
    const int gb = lane & 48;

    // MFMA mapping
    const int rt = wave & 1;
    const int ch = wave >> 1;
    const int lr = lane & 15;
    const int kc = (lane >> 4) * 8;

    const int gn0 = nbase + g;
    const int gn1 = nbase + 16 + g;
    const int sg0 = gn0 < N_NODES ? gn0 : 0;   // clamped for safe prefetch
    const int sg1 = gn1 < N_NODES ? gn1 : 0;

    // ---- prefetch r=0 cnt + ell word (lane j: slots 2j,2j+1) ----
    int  pc0 = cnt[sg0];
    int  pc1 = cnt[sg1];
    uint pe0 = *(const uint*)(ell + (size_t)sg0 * CAP + 2 * j);
    uint pe1 = *(const uint*)(ell + (size_t)sg1 * CAP + 2 * j);

    f32x4 acc[NCH];
#pragma unroll
    for (int t = 0; t < NCH; ++t) acc[t] = (f32x4){0.f, 0.f, 0.f, 0.f};

    for (int r = 0; r <= N_REL; ++r) {
        // ---- gather-mean 32 nodes into meanT (two passes, 4-deep) ----
#pragma unroll
        for (int p = 0; p < 2; ++p) {
            int gn = p ? gn1 : gn0;
            int a  = p * 16 + g;
            short8 sv = (short8){0, 0, 0, 0, 0, 0, 0, 0};
            if (gn < N_NODES) {
                if (r == N_REL) {
                    sv = *(const short8*)(xbf + (size_t)gn * 128 + j8);
                } else {
                    int  c   = p ? pc1 : pc0;
                    uint pre = p ? pe1 : pe0;
                    int  cc  = c < CAP ? c : CAP;
                    f32x4 s0 = (f32x4){0.f, 0.f, 0.f, 0.f};
                    f32x4 s1 = (f32x4){0.f, 0.f, 0.f, 0.f};
                    int ccr = (cc + 3) & ~3;
                    for (int e = 0; e < ccr; e += 4) {
                        uint ua = __shfl(pre, gb + (e >> 1), 64);
                        uint ub = __shfl(pre, gb + (e >> 1) + 1, 64);
                        int i0 = (e + 0 < cc) ? (int)(ua & 0xFFFFu) : N_NODES;
                        int i1 = (e + 1 < cc) ? (int)(ua >> 16)     : N_NODES;
                        int i2 = (e + 2 < cc) ? (int)(ub & 0xFFFFu) : N_NODES;
                        int i3 = (e + 3 < cc) ? (int)(ub >> 16)     : N_NODES;
                        short8 v0 = *(const short8*)(xbf + (size_t)i0 * 128 + j8);
                        short8 v1 = *(const short8*)(xbf + (size_t)i1 * 128 + j8);
                        short8 v2 = *(const short8*)(xbf + (size_t)i2 * 128 + j8);
                        short8 v3 = *(const short8*)(xbf + (size_t)i3 * 128 + j8);
#pragma unroll
                        for (int u = 0; u < 4; ++u) {
                            short8 v = (u == 0) ? v0 : (u == 1) ? v1
                                     : (u == 2) ? v2 : v3;
                            uint4 w = __builtin_bit_cast(uint4, v);
                            s0.x += u2f(w.x << 16);
                            s0.y += u2f(w.x & 0xFFFF0000u);
                            s0.z += u2f(w.y << 16);
                            s0.w += u2f(w.y & 0xFFFF0000u);
                            s1.x += u2f(w.z << 16);
                            s1.y += u2f(w.z & 0xFFFF0000u);
                            s1.z += u2f(w.w << 16);
                            s1.w += u2f(w.w & 0xFFFF0000u);
                        }
                    }
                    float inv = 1.f / (float)(c > 1 ? c : 1);
                    s0 *= inv;
                    s1 *= inv;
                    sv = (short8){(short)f2bf(s0.x), (short)f2bf(s0.y),
                                  (short)f2bf(s0.z), (short)f2bf(s0.w),
                                  (short)f2bf(s1.x), (short)f2bf(s1.y),
                                  (short)f2bf(s1.z), (short)f2bf(s1.w)};
                }
            }
            *(short8*)&meanT[a * LDK + j8] = sv;
        }

        // ---- prefetch next relation's cnt + ell word (hidden under MFMA) ----
        if (r + 1 < N_REL) {
            size_t so = (size_t)(r + 1) * N_NODES;
            pc0 = cnt[so + sg0];
            pc1 = cnt[so + sg1];
            pe0 = *(const uint*)(ell + (so + sg0) * CAP + 2 * j);
            pe1 = *(const uint*)(ell + (so + sg1) * CAP + 2 * j);
        }
        __syncthreads();   // meanT ready; prev r's MFMA done -> Wl writable

        // A-fragments for this r
        short8 af[4];
        const int m = rt * 16 + lr;
#pragma unroll
        for (int ks = 0; ks < 4; ++ks)
            af[ks] = *(const short8*)&meanT[m * LDK + ks * 32 + kc];

        // ---- per 32-row W chunk: stage -> sync -> MFMA (-> sync) ----
#pragma unroll
        for (int c = 0; c < NCH; ++c) {
            {   // stage 32 rows of W_r^T (coalesced float4, 2 per thread)
                const float4* src =
                    (const float4*)(Wt + ((size_t)r * OUTC + c * 32) * 128);
#pragma unroll
                for (int q = 0; q < 2; ++q) {
                    int idx = tid + q * 256;
                    int n   = idx >> 4;
                    int k8  = idx & 15;
                    *(float4*)&Wl[n * LDK + k8 * 8] = src[idx];
                }
            }
            __syncthreads();          // Wl ready
            const int n = ch * 16 + lr;     // row within chunk
            f32x4 a = acc[c];
#pragma unroll
            for (int ks = 0; ks < 4; ++ks) {
                short8 bf = *(const short8*)&Wl[n * LDK + ks * 32 + kc];
                a = __builtin_amdgcn_mfma_f32_16x16x32_bf16(af[ks], bf, a,
                                                            0, 0, 0);
            }
            acc[c] = a;
            if (c + 1 < NCH) __syncthreads();  // MFMA done reading Wl
        }
    }

    // ---- epilogue: bias (+relu), nontemporal stores ----
    const int rq = (lane >> 4) * 4;
#pragma unroll
    for (int t = 0; t < NCH; ++t) {
        int col  = t * 32 + ch * 16 + lr;
        float bv = bias[col];
#pragma unroll
        for (int q = 0; q < 4; ++q) {
            int node = nbase + rt * 16 + rq + q;
            if (node < N_NODES) {
                float v = acc[t][q] + bv;
                if (RELU) v = fmaxf(v, 0.f);
                if (BF16OUT)
                    __builtin_nontemporal_store(
                        f2bf(v), (ushort*)outp + (size_t)node * OUTC + col);
                else
                    __builtin_nontemporal_store(
                        v, (float*)outp + (size_t)node * OUTC + col);
            }
        }
    }
}

extern "C" void kernel_launch(void* const* d_in, const int* in_sizes, int n_in,
                              void* d_out, int out_size, void* d_ws, size_t ws_size,
                              hipStream_t stream) {
    const float* x        = (const float*)d_in[0];
    const int*   A        = (const int*)d_in[1];
    const int*   etype    = (const int*)d_in[2];
    const float* w1_basis = (const float*)d_in[3];
    const float* w1_comp  = (const float*)d_in[4];
    const float* w1_root  = (const float*)d_in[5];
    const float* w1_bias  = (const float*)d_in[6];
    const float* w2_basis = (const float*)d_in[7];
    const float* w2_comp  = (const float*)d_in[8];
    const float* w2_root  = (const float*)d_in[9];
    const float* w2_bias  = (const float*)d_in[10];
    float* out = (float*)d_out;

    char* ws = (char*)d_ws;
    ushort* Wt1  = (ushort*)(ws);                   // 294,912 B
    ushort* Wt2  = (ushort*)(ws + (512 << 10));     // 147,456 B
    int*    cnt  = (int*)(ws + (1 << 20));          // 1.6 MB (NSEG)
    ushort* x_bf = (ushort*)(ws + (3ull << 20));    // 12.8 MB ((N+1)*128)
    ushort* h_bf = (ushort*)(ws + (16ull << 20));   // 12.8 MB
    ushort* ell  = (ushort*)(ws + (29ull << 20));   // 25.6 MB u16

    zero_i32_kernel<<<(NSEG + 255) / 256, 256, 0, stream>>>(cnt, NSEG);
    mega_prep_kernel<<<NB_BUILD + NB_X + NB_W, 256, 0, stream>>>(
        A, etype, cnt, ell, x, x_bf, h_bf,
        w1_basis, w1_comp, w1_root, w2_basis, w2_comp, w2_root, Wt1, Wt2);

    int grid = (N_NODES + 31) / 32;  // 1563
    rgcn_layer_mfma<128, true, true><<<grid, 256, 0, stream>>>(
        x_bf, cnt, ell, Wt1, w1_bias, h_bf);
    rgcn_layer_mfma<64, false, false><<<grid, 256, 0, stream>>>(
        h_bf, cnt, ell, Wt2, w2_bias, out);
}